// Round 5
// baseline (282.416 us; speedup 1.0000x reference)
//
#include <hip/hip_runtime.h>
#include <hip/hip_bf16.h>
#include <hip/hip_fp16.h>

#define T_SEQ 4096
#define DMODEL 1024
#define HEAD 64
#define NBATCH 4
#define NSEG 544              // per batch: sum_{t<64} ((t>>2)+1), tier=4 tiles
#define S2LOG 0.04508422f     // (1/sqrt(1024)) * log2(e), folded into q

typedef __attribute__((ext_vector_type(8))) short bf16x8;
typedef __attribute__((ext_vector_type(4))) float f32x4;

__device__ __forceinline__ unsigned short f2bf(float f) {
    unsigned int b = __float_as_uint(f);
    unsigned int r = b + 0x7FFFu + ((b >> 16) & 1u);
    return (unsigned short)(r >> 16);
}
__device__ __forceinline__ unsigned int pk_bf16(float a, float b) {
    __hip_bfloat162 h = __float22bfloat162_rn(make_float2(a, b));
    unsigned int u; __builtin_memcpy(&u, &h, 4); return u;
}
// async global->LDS DMA, 16B/lane, dest = base + lane*16 (zero VGPR results)
__device__ __forceinline__ void dma16(const void* g, void* s) {
    __builtin_amdgcn_global_load_lds(
        (const __attribute__((address_space(1))) unsigned int*)g,
        (__attribute__((address_space(3))) unsigned int*)s, 16, 0, 0);
}

// ---------------- Kernel 0: W -> Wt[8 sg][192 col][128 k] bf16 ---------------
// K-stage-major layout: each 48 KB K-stage slice is contiguous, so qkv's DMA
// staging is perfectly coalesced (1 KB per global_load_lds instruction).
// Also zeroes the split-K arrival counters (must happen every graph replay,
// before flash_seg).
__global__ __launch_bounds__(256) void prep_w(
    const float* __restrict__ Wq, const float* __restrict__ Wk,
    const float* __restrict__ Wv, unsigned short* __restrict__ Wtb,
    int* __restrict__ cnt)
{
    __shared__ unsigned short tl[64 * 72];
    const int bid = blockIdx.x;
    const int m   = bid >> 4;
    const int k0  = (bid & 15) * 64;
    const float* W = (m == 0) ? Wq : (m == 1) ? Wk : Wv;
    const int t  = threadIdx.x;
    if (bid == 0) cnt[t] = 0;                 // 256 counters = (batch, tile)
    const int kr = t >> 2, qtr = t & 3;
#pragma unroll
    for (int i = 0; i < 4; ++i) {
        float4 wv4 = *(const float4*)&W[(k0 + kr) * 64 + qtr * 16 + i * 4];
        tl[(qtr * 16 + i * 4 + 0) * 72 + kr] = f2bf(wv4.x);
        tl[(qtr * 16 + i * 4 + 1) * 72 + kr] = f2bf(wv4.y);
        tl[(qtr * 16 + i * 4 + 2) * 72 + kr] = f2bf(wv4.z);
        tl[(qtr * 16 + i * 4 + 3) * 72 + kr] = f2bf(wv4.w);
    }
    __syncthreads();
#pragma unroll
    for (int c = 0; c < 2; ++c) {
        const int lin = c * 256 + t;
        const int n = lin >> 3, k8 = lin & 7;
        const int k = k0 + k8 * 8;
        const int sg = k >> 7, koff = k & 127;
        *(uint4*)&Wtb[((long)(sg * 192 + m * 64 + n)) * 128 + koff] =
            *(const uint4*)&tl[n * 72 + k8 * 8];
    }
}

// ---------------- Kernel 1: QKV projection, W-in-LDS bf16 MFMA --------------
// (round-2 known-good version: 27 us, 166 MB staged at ~24 GB/s/CU law)
// 256 blocks x 64 rows, 512 threads (8 waves = 2 rowg x 4 colg). W K-slices
// staged into LDS via contiguous global_load_lds (dbuf, source pre-swizzled,
// linear dest). x reg-staged, converted once, ds_written XOR-swizzled.
// One barrier per K-stage; prefetch issued right after it.
__global__ __launch_bounds__(512, 2) void qkv_mfma(
    const float* __restrict__ x, const unsigned short* __restrict__ Wtb,
    const float* __restrict__ bq, const float* __restrict__ bk,
    const float* __restrict__ bv,
    unsigned short* __restrict__ qo, unsigned short* __restrict__ ko,
    unsigned short* __restrict__ vt)
{
    __shared__ __align__(16) unsigned short xs[2][8192];    // 64r x 128k, 2x16KB
    __shared__ __align__(16) unsigned short wsd[2][24576];  // 192c x 128k, 2x48KB
    const int t    = threadIdx.x;
    const int lane = t & 63;
    const int l15  = lane & 15, quad = lane >> 4;
    const int wv   = __builtin_amdgcn_readfirstlane(t >> 6);
    const int rowg = wv >> 2;                  // 0..1 -> +32 rows
    const int colg = wv & 3;                   // 0..3 -> +48 cols
    const long row0 = (long)blockIdx.x * 64;

    float bias[3];
#pragma unroll
    for (int ntl = 0; ntl < 3; ++ntl) {
        const int c = colg * 48 + ntl * 16 + l15;
        bias[ntl] = (c < 64) ? bq[c] : (c < 128) ? bk[c - 64] : bv[c - 128];
    }
    f32x4 acc[2][3];
#pragma unroll
    for (int mt = 0; mt < 2; ++mt)
#pragma unroll
        for (int ntl = 0; ntl < 3; ++ntl)
            acc[mt][ntl] = (f32x4){bias[ntl], bias[ntl], bias[ntl], bias[ntl]};

    // x staging: 2048 16B-slots (64 rows x 32 chunk-halves), 4 per thread.
    float4 g[4];
    auto load_stage = [&](int sg) {
#pragma unroll
        for (int s = 0; s < 4; ++s) {
            const int id = s * 512 + t, row = id >> 5, off = id & 31;
            g[s] = *(const float4*)&x[(row0 + row) * DMODEL + sg * 128 + off * 4];
        }
    };
    // logical 16B-bf16 chunk c of row r stored at chunk (c ^ (r&7)).
    auto write_stage = [&](int buf) {
#pragma unroll
        for (int s = 0; s < 4; ++s) {
            const int id = s * 512 + t, row = id >> 5, off = id & 31;
            uint2 u;
            u.x = pk_bf16(g[s].x, g[s].y);
            u.y = pk_bf16(g[s].z, g[s].w);
            *(uint2*)&xs[buf][row * 128 + ((off >> 1) ^ (row & 7)) * 8 + (off & 1) * 4] = u;
        }
    };
    // W staging: 3072 16B-slots (192 cols x 16 chunks), 48 DMA instrs (6/wave).
    // LDS linear; source pre-swizzled so LDS[col][ch] = W[col][ch ^ (col&7)].
    auto dma_w = [&](int sg, int buf) {
#pragma unroll
        for (int j = 0; j < 6; ++j) {
            const int slot0 = (wv * 6 + j) * 64;
            const int slot  = slot0 + lane;
            const int col   = slot >> 4, ch = slot & 15;
            dma16(Wtb + ((long)(sg * 192 + col)) * 128 + ((ch ^ (col & 7)) * 8),
                  &wsd[buf][slot0 * 8]);
        }
    };

    load_stage(0);
    dma_w(0, 0);
    write_stage(0);

    for (int sg = 0; sg < 8; ++sg) {
        __syncthreads();                      // drains DMA + x writes for sg
        if (sg + 1 < 8) {                     // prefetch next stage
            load_stage(sg + 1);
            dma_w(sg + 1, (sg + 1) & 1);
        }
        bf16x8 wf[3][4];
#pragma unroll
        for (int ntl = 0; ntl < 3; ++ntl)
#pragma unroll
            for (int kq = 0; kq < 4; ++kq) {
                const int col = colg * 48 + ntl * 16 + l15;
                wf[ntl][kq] = *(const bf16x8*)&wsd[sg & 1][col * 128
                                                           + (((kq * 4 + quad) ^ (col & 7))) * 8];
            }
#pragma unroll
        for (int mt = 0; mt < 2; ++mt)
#pragma unroll
            for (int kq = 0; kq < 4; ++kq) {
                const int row = rowg * 32 + mt * 16 + l15;
                bf16x8 a = *(const bf16x8*)&xs[sg & 1][row * 128
                                                       + ((kq * 4 + quad) ^ (row & 7)) * 8];
#pragma unroll
                for (int ntl = 0; ntl < 3; ++ntl)
                    acc[mt][ntl] = __builtin_amdgcn_mfma_f32_16x16x32_bf16(a, wf[ntl][kq], acc[mt][ntl], 0, 0, 0);
            }
        if (sg + 1 < 8) write_stage((sg + 1) & 1);  // other buffer; pre-barrier ok
    }
    // epilogue: C/D col=l15, row=quad*4+r
#pragma unroll
    for (int mt = 0; mt < 2; ++mt)
#pragma unroll
        for (int ntl = 0; ntl < 3; ++ntl) {
            const int c = colg * 48 + ntl * 16 + l15;
            const long tr0 = row0 + rowg * 32 + mt * 16 + quad * 4;
            if (c < 64) {
#pragma unroll
                for (int r = 0; r < 4; ++r)
                    qo[(tr0 + r) * HEAD + c] = f2bf(acc[mt][ntl][r] * S2LOG);
            } else if (c < 128) {
#pragma unroll
                for (int r = 0; r < 4; ++r)
                    ko[(tr0 + r) * HEAD + (c - 64)] = f2bf(acc[mt][ntl][r]);
            } else {
                const int b = (int)(tr0 >> 12), tloc = (int)(tr0 & 4095);
                uint2 pv;
                pv.x = pk_bf16(acc[mt][ntl][0], acc[mt][ntl][1]);
                pv.y = pk_bf16(acc[mt][ntl][2], acc[mt][ntl][3]);
                *(uint2*)&vt[((long)(b * HEAD + (c - 128))) * T_SEQ + tloc] = pv;
            }
        }
}

// ---------------- Kernel 2: flash attention + fused split-K merge -----------
// 2176 blocks (544 segments x 4 batches), 256 threads. Block = one (segment,
// batch), 64-row q-tile. Wave = (q-half 32 rows) x (key-half 32 keys): each
// wave reads ONLY its 4 KB K-slice + 4 KB V-slice from LDS. K+V chunk (16 KB)
// staged via global_load_lds dbuf, XOR-swizzled. Cross-wave O/l merge via LDS
// at the end (kv_s reused). NO-MAX softmax: p = exp2(s) directly.
// FUSED MERGE: after writing its partial, each block does release-fence +
// atomicAdd on cnt[b*64+tile]; the LAST of the S split-K blocks acquires and
// merges all S partials (L2-warm) into out. Removes the merge kernel launch.
__global__ __launch_bounds__(256, 3) void flash_seg(
    const unsigned short* __restrict__ qg,
    const unsigned short* __restrict__ kg,
    const unsigned short* __restrict__ vtg,
    __half* __restrict__ opart, float* __restrict__ ml,
    float* __restrict__ out, int* __restrict__ cnt)
{
    __shared__ __align__(16) unsigned short kv_s[2][8192]; // [buf][K 4096|V 4096]
    __shared__ __align__(16) unsigned short p_s[4][32 * 40];
    __shared__ __align__(16) float l_lds[2][32];
    __shared__ int last_flag;
    const int t0   = threadIdx.x;
    const int lane = t0 & 63;
    const int l15  = lane & 15, quad = lane >> 4;
    const int wv   = __builtin_amdgcn_readfirstlane(t0 >> 6);
    const int qh   = wv & 1;                   // q-half (32 rows)
    const int kh2  = wv >> 1;                  // key-half (32 keys)

    const int bid = (int)blockIdx.x;
    const int sid = (NSEG - 1) - (bid >> 2);   // heavy first
    const int b   = bid & 3;

    int kk = 0, pref = 0;
#pragma unroll
    for (int i = 0; i < 15; ++i) {
        const int cnt_t = 4 * (kk + 1);
        if (sid >= pref + cnt_t) { pref += cnt_t; ++kk; }
    }
    const int S   = kk + 1;
    const int rem = sid - pref;
    const int t   = kk * 4 + rem / S;
    const int si  = rem % S;
    const int r0  = t * 64;
    const int rw  = r0 + qh * 32;              // this wave's first q-row
    const int nck = t + 1;
    const int c0  = (si * nck) / S, c1 = ((si + 1) * nck) / S;
    const long bbase = (long)b * T_SEQ;
    const int gidx = b * NSEG + sid;

    // Q B-frags: [cg: 16-row group][h: 32-dim half]
    bf16x8 qf[2][2];
#pragma unroll
    for (int cg = 0; cg < 2; ++cg)
#pragma unroll
        for (int h = 0; h < 2; ++h)
            qf[cg][h] = *(const bf16x8*)&qg[(bbase + rw + cg * 16 + l15) * HEAD
                                            + h * 32 + quad * 8];

    f32x4 o[4][2];                             // [dt: 16-dim group][cg]
#pragma unroll
    for (int dt = 0; dt < 4; ++dt)
#pragma unroll
        for (int cg = 0; cg < 2; ++cg) o[dt][cg] = (f32x4){0.f, 0.f, 0.f, 0.f};
    float lrun[2] = {0.f, 0.f};
    unsigned short* ps = p_s[wv];

    // DMA one K+V chunk: wave wv issues K jj={2wv,2wv+1}, V jj={2wv,2wv+1}.
    auto dma_chunk = [&](int key0, int buf) {
#pragma unroll
        for (int i = 0; i < 2; ++i) {
            const int jj  = wv * 2 + i;
            const int kl  = jj * 8 + (lane >> 3);
            const int dlg = (lane & 7) ^ ((lane >> 3) & 7);
            dma16(kg + (bbase + key0 + kl) * HEAD + dlg * 8,
                  &kv_s[buf][jj * 512]);
        }
#pragma unroll
        for (int i = 0; i < 2; ++i) {
            const int jj  = wv * 2 + i;
            const int dim = jj * 8 + (lane >> 3);
            const int klg = (lane & 7) ^ ((lane >> 3) & 7);
            dma16(vtg + ((long)(b * HEAD + dim)) * T_SEQ + key0 + klg * 8,
                  &kv_s[buf][4096 + jj * 512]);
        }
    };
    dma_chunk(c0 * 64, 0);

    for (int c = c0; c < c1; ++c) {
        const int key0 = c * 64;
        const int cur  = (c - c0) & 1;
        __syncthreads();                       // drain DMA(cur) + sync waves
        if (c + 1 < c1) dma_chunk((c + 1) * 64, cur ^ 1);

        // K A-frags: only this wave's 32-key half (zero redundancy).
        bf16x8 kf[2][2];                       // [mt: 16-key group][kd: 32-dim half]
#pragma unroll
        for (int mt = 0; mt < 2; ++mt)
#pragma unroll
            for (int kd = 0; kd < 2; ++kd) {
                const int key_l = kh2 * 32 + mt * 16 + l15;
                kf[mt][kd] = *(const bf16x8*)&kv_s[cur][key_l * 64
                                                        + ((kd * 4 + quad) ^ (l15 & 7)) * 8];
            }
        // S^T = K Q^T
        f32x4 st[2][2];                        // [mt][cg]
#pragma unroll
        for (int mt = 0; mt < 2; ++mt)
#pragma unroll
            for (int cg = 0; cg < 2; ++cg) {
                f32x4 z = (f32x4){0.f, 0.f, 0.f, 0.f};
                z = __builtin_amdgcn_mfma_f32_16x16x32_bf16(kf[mt][0], qf[cg][0], z, 0, 0, 0);
                st[mt][cg] = __builtin_amdgcn_mfma_f32_16x16x32_bf16(kf[mt][1], qf[cg][1], z, 0, 0, 0);
            }
        // V A-frags: only this wave's 32-key half.
        bf16x8 vf[4];
#pragma unroll
        for (int dt = 0; dt < 4; ++dt) {
            const int dim = dt * 16 + l15;
            vf[dt] = *(const bf16x8*)&kv_s[cur][4096 + dim * 64
                                                 + ((kh2 * 4 + quad) ^ (l15 & 7)) * 8];
        }
        if (key0 + kh2 * 32 + 31 > rw) {       // causal mask (diagonal region)
#pragma unroll
            for (int mt = 0; mt < 2; ++mt)
#pragma unroll
                for (int cg = 0; cg < 2; ++cg)
#pragma unroll
                    for (int r = 0; r < 4; ++r) {
                        const int key = key0 + kh2 * 32 + mt * 16 + quad * 4 + r;
                        const int row = rw + cg * 16 + l15;
                        st[mt][cg][r] = (key <= row) ? st[mt][cg][r] : -30000.f;
                    }
        }
        // no-max softmax: p = exp2(s); per-lane partial -> quad reduce.
        float psum[2] = {0.f, 0.f};
#pragma unroll
        for (int mt = 0; mt < 2; ++mt)
#pragma unroll
            for (int cg = 0; cg < 2; ++cg) {
                float e0 = exp2f(st[mt][cg][0]), e1 = exp2f(st[mt][cg][1]);
                float e2 = exp2f(st[mt][cg][2]), e3 = exp2f(st[mt][cg][3]);
                psum[cg] += (e0 + e1) + (e2 + e3);
                *(unsigned int*)&ps[(cg * 16 + l15) * 40 + mt * 16 + quad * 4]     = pk_bf16(e0, e1);
                *(unsigned int*)&ps[(cg * 16 + l15) * 40 + mt * 16 + quad * 4 + 2] = pk_bf16(e2, e3);
            }
#pragma unroll
        for (int cg = 0; cg < 2; ++cg) {
            psum[cg] += __shfl_xor(psum[cg], 16);
            psum[cg] += __shfl_xor(psum[cg], 32);
            lrun[cg] += psum[cg];
        }
        __builtin_amdgcn_wave_barrier();
        bf16x8 pf[2];
#pragma unroll
        for (int cg = 0; cg < 2; ++cg)
            pf[cg] = *(const bf16x8*)&ps[(cg * 16 + l15) * 40 + quad * 8];
        __builtin_amdgcn_wave_barrier();
#pragma unroll
        for (int dt = 0; dt < 4; ++dt)
#pragma unroll
            for (int cg = 0; cg < 2; ++cg)
                o[dt][cg] = __builtin_amdgcn_mfma_f32_16x16x32_bf16(vf[dt], pf[cg], o[dt][cg], 0, 0, 0);
    }

    // ---- cross-wave merge (key-halves) via LDS; kv_s is dead now ----------
    __syncthreads();
    float* o_lds = (float*)&kv_s[0][0];        // [64 rows][68 f32] (17.4 KB)
    if (kh2 == 1) {
#pragma unroll
        for (int dt = 0; dt < 4; ++dt)
#pragma unroll
            for (int cg = 0; cg < 2; ++cg)
                *(f32x4*)&o_lds[(qh * 32 + cg * 16 + l15) * 68 + dt * 16 + quad * 4] = o[dt][cg];
        if (quad == 0) {
#pragma unroll
            for (int cg = 0; cg < 2; ++cg)
                l_lds[qh][cg * 16 + l15] = lrun[cg];
        }
    }
    __syncthreads();
    if (kh2 == 0) {
        float inv[2];
#pragma unroll
        for (int cg = 0; cg < 2; ++cg) {
            lrun[cg] += l_lds[qh][cg * 16 + l15];
            inv[cg] = (lrun[cg] > 0.f) ? 1.f / lrun[cg] : 0.f;
        }
        __half* op = opart + (long)gidx * 4096;
#pragma unroll
        for (int dt = 0; dt < 4; ++dt)
#pragma unroll
            for (int cg = 0; cg < 2; ++cg) {
                f32x4 ov = o[dt][cg];
                f32x4 add = *(const f32x4*)&o_lds[(qh * 32 + cg * 16 + l15) * 68 + dt * 16 + quad * 4];
                ov += add;
                __half2 h0 = __floats2half2_rn(ov[0] * inv[cg], ov[1] * inv[cg]);
                __half2 h1 = __floats2half2_rn(ov[2] * inv[cg], ov[3] * inv[cg]);
                uint2 u; __builtin_memcpy(&u.x, &h0, 4); __builtin_memcpy(&u.y, &h1, 4);
                *(uint2*)&op[(qh * 32 + cg * 16 + l15) * HEAD + dt * 16 + quad * 4] = u;
            }
        if (quad == 0) {
#pragma unroll
            for (int cg = 0; cg < 2; ++cg)
                ml[(long)gidx * 64 + qh * 32 + cg * 16 + l15] = lrun[cg];
        }
    }

    // ---- fused split-K merge: last block of this (b, tile) merges ---------
    __syncthreads();                           // all partial stores drained
    if (t0 == 0) {
        __threadfence();                       // release: partials visible
        const int old = atomicAdd(&cnt[b * 64 + t], 1);
        last_flag = (old == S - 1) ? 1 : 0;
    }
    __syncthreads();
    if (last_flag) {
        __threadfence();                       // acquire: invalidate stale lines
        const int base_sid = 2 * kk * (kk + 1) + (t & 3) * S;
        const int row = t0 >> 2, col0 = (t0 & 3) * 16;
        float acc[16];
#pragma unroll
        for (int j = 0; j < 16; ++j) acc[j] = 0.f;
        float L = 0.f;
        for (int s2 = 0; s2 < S; ++s2) {
            const long g = (long)(b * NSEG + base_sid + s2);
            const float l = ml[g * 64 + row];
            L += l;
            const __half* op = opart + g * 4096 + row * 64 + col0;
#pragma unroll
            for (int h = 0; h < 2; ++h) {
                uint4 u = *(const uint4*)(op + h * 8);
                __half2 h01, h23, h45, h67;
                __builtin_memcpy(&h01, &u.x, 4); __builtin_memcpy(&h23, &u.y, 4);
                __builtin_memcpy(&h45, &u.z, 4); __builtin_memcpy(&h67, &u.w, 4);
                float2 f01 = __half22float2(h01), f23 = __half22float2(h23);
                float2 f45 = __half22float2(h45), f67 = __half22float2(h67);
                acc[h * 8 + 0] += l * f01.x; acc[h * 8 + 1] += l * f01.y;
                acc[h * 8 + 2] += l * f23.x; acc[h * 8 + 3] += l * f23.y;
                acc[h * 8 + 4] += l * f45.x; acc[h * 8 + 5] += l * f45.y;
                acc[h * 8 + 6] += l * f67.x; acc[h * 8 + 7] += l * f67.y;
            }
        }
        const float inv = 1.f / L;  // L > 0: every q-row sees its diagonal key
        float* dst = out + ((long)(b * T_SEQ + t * 64 + row)) * HEAD + col0;
#pragma unroll
        for (int h = 0; h < 4; ++h) {
            float4 ov = {acc[h * 4] * inv, acc[h * 4 + 1] * inv,
                         acc[h * 4 + 2] * inv, acc[h * 4 + 3] * inv};
            *(float4*)(dst + h * 4) = ov;
        }
    }
}

extern "C" void kernel_launch(void* const* d_in, const int* in_sizes, int n_in,
                              void* d_out, int out_size, void* d_ws, size_t ws_size,
                              hipStream_t stream) {
    const float* x  = (const float*)d_in[0];
    const float* Wq = (const float*)d_in[1];
    const float* bq = (const float*)d_in[2];
    const float* Wk = (const float*)d_in[3];
    const float* bk = (const float*)d_in[4];
    const float* Wv = (const float*)d_in[5];
    const float* bv = (const float*)d_in[6];
    float* outp = (float*)d_out;

    char* wsb = (char*)d_ws;
    unsigned short* wtb = (unsigned short*)(wsb);                  // 384 KB
    unsigned short* qw  = (unsigned short*)(wsb + 393216);         // 2 MB
    unsigned short* kw  = (unsigned short*)(wsb + 2490368);        // 2 MB
    unsigned short* vtw = (unsigned short*)(wsb + 4587520);        // 2 MB
    __half* opart       = (__half*)(wsb + 6684672);                // 17.8 MB
    float*  mlp         = (float*)(wsb + 24510464);                // 0.6 MB
    int*    cntp        = (int*)(wsb + 25067520);                  // 1 KB

    prep_w<<<dim3(48), dim3(256), 0, stream>>>(Wq, Wk, Wv, wtb, cntp);
    qkv_mfma<<<dim3(256), dim3(512), 0, stream>>>(
        x, wtb, bq, bk, bv, qw, kw, vtw);
    flash_seg<<<dim3(NSEG * NBATCH), dim3(256), 0, stream>>>(
        qw, kw, vtw, opart, mlp, outp, cntp);
}

// Round 6
// 146.724 us; speedup vs baseline: 1.9248x; 1.9248x over previous
//
#include <hip/hip_runtime.h>
#include <hip/hip_bf16.h>
#include <hip/hip_fp16.h>

#define T_SEQ 4096
#define DMODEL 1024
#define HEAD 64
#define NBATCH 4
#define NSEG 544              // per batch: sum_{t<64} ((t>>2)+1), tier=4 tiles
#define S2LOG 0.04508422f     // (1/sqrt(1024)) * log2(e), folded into q

typedef __attribute__((ext_vector_type(8))) short bf16x8;
typedef __attribute__((ext_vector_type(4))) float f32x4;

__device__ __forceinline__ unsigned short f2bf(float f) {
    unsigned int b = __float_as_uint(f);
    unsigned int r = b + 0x7FFFu + ((b >> 16) & 1u);
    return (unsigned short)(r >> 16);
}
__device__ __forceinline__ unsigned int pk_bf16(float a, float b) {
    __hip_bfloat162 h = __float22bfloat162_rn(make_float2(a, b));
    unsigned int u; __builtin_memcpy(&u, &h, 4); return u;
}
// async global->LDS DMA, 16B/lane, dest = base + lane*16 (zero VGPR results)
__device__ __forceinline__ void dma16(const void* g, void* s) {
    __builtin_amdgcn_global_load_lds(
        (const __attribute__((address_space(1))) unsigned int*)g,
        (__attribute__((address_space(3))) unsigned int*)s, 16, 0, 0);
}

// ---------------- Kernel 0: W -> Wt[8 sg][192 col][128 k] bf16 ---------------
// K-stage-major layout: each 48 KB K-stage slice is contiguous, so qkv's DMA
// staging is perfectly coalesced (1 KB per global_load_lds instruction).
__global__ __launch_bounds__(256) void prep_w(
    const float* __restrict__ Wq, const float* __restrict__ Wk,
    const float* __restrict__ Wv, unsigned short* __restrict__ Wtb)
{
    __shared__ unsigned short tl[64 * 72];
    const int bid = blockIdx.x;
    const int m   = bid >> 4;
    const int k0  = (bid & 15) * 64;
    const float* W = (m == 0) ? Wq : (m == 1) ? Wk : Wv;
    const int t  = threadIdx.x;
    const int kr = t >> 2, qtr = t & 3;
#pragma unroll
    for (int i = 0; i < 4; ++i) {
        float4 wv4 = *(const float4*)&W[(k0 + kr) * 64 + qtr * 16 + i * 4];
        tl[(qtr * 16 + i * 4 + 0) * 72 + kr] = f2bf(wv4.x);
        tl[(qtr * 16 + i * 4 + 1) * 72 + kr] = f2bf(wv4.y);
        tl[(qtr * 16 + i * 4 + 2) * 72 + kr] = f2bf(wv4.z);
        tl[(qtr * 16 + i * 4 + 3) * 72 + kr] = f2bf(wv4.w);
    }
    __syncthreads();
#pragma unroll
    for (int c = 0; c < 2; ++c) {
        const int lin = c * 256 + t;
        const int n = lin >> 3, k8 = lin & 7;
        const int k = k0 + k8 * 8;
        const int sg = k >> 7, koff = k & 127;
        *(uint4*)&Wtb[((long)(sg * 192 + m * 64 + n)) * 128 + koff] =
            *(const uint4*)&tl[n * 72 + k8 * 8];
    }
}

// ---------------- Kernel 1: QKV projection, W-in-LDS bf16 MFMA --------------
// (round-2 known-good: 256 blocks x 64 rows, 512 threads, 8 waves = 2 rowg x
// 4 colg). W K-slices staged into LDS via contiguous global_load_lds (dbuf,
// source pre-swizzled, linear dest). x reg-staged, converted once, ds_written
// XOR-swizzled. One barrier per K-stage; prefetch issued right after it.
__global__ __launch_bounds__(512, 2) void qkv_mfma(
    const float* __restrict__ x, const unsigned short* __restrict__ Wtb,
    const float* __restrict__ bq, const float* __restrict__ bk,
    const float* __restrict__ bv,
    unsigned short* __restrict__ qo, unsigned short* __restrict__ ko,
    unsigned short* __restrict__ vt)
{
    __shared__ __align__(16) unsigned short xs[2][8192];    // 64r x 128k, 2x16KB
    __shared__ __align__(16) unsigned short wsd[2][24576];  // 192c x 128k, 2x48KB
    const int t    = threadIdx.x;
    const int lane = t & 63;
    const int l15  = lane & 15, quad = lane >> 4;
    const int wv   = __builtin_amdgcn_readfirstlane(t >> 6);
    const int rowg = wv >> 2;                  // 0..1 -> +32 rows
    const int colg = wv & 3;                   // 0..3 -> +48 cols
    const long row0 = (long)blockIdx.x * 64;

    float bias[3];
#pragma unroll
    for (int ntl = 0; ntl < 3; ++ntl) {
        const int c = colg * 48 + ntl * 16 + l15;
        bias[ntl] = (c < 64) ? bq[c] : (c < 128) ? bk[c - 64] : bv[c - 128];
    }
    f32x4 acc[2][3];
#pragma unroll
    for (int mt = 0; mt < 2; ++mt)
#pragma unroll
        for (int ntl = 0; ntl < 3; ++ntl)
            acc[mt][ntl] = (f32x4){bias[ntl], bias[ntl], bias[ntl], bias[ntl]};

    // x staging: 2048 16B-slots (64 rows x 32 chunk-halves), 4 per thread.
    float4 g[4];
    auto load_stage = [&](int sg) {
#pragma unroll
        for (int s = 0; s < 4; ++s) {
            const int id = s * 512 + t, row = id >> 5, off = id & 31;
            g[s] = *(const float4*)&x[(row0 + row) * DMODEL + sg * 128 + off * 4];
        }
    };
    // logical 16B-bf16 chunk c of row r stored at chunk (c ^ (r&7)).
    auto write_stage = [&](int buf) {
#pragma unroll
        for (int s = 0; s < 4; ++s) {
            const int id = s * 512 + t, row = id >> 5, off = id & 31;
            uint2 u;
            u.x = pk_bf16(g[s].x, g[s].y);
            u.y = pk_bf16(g[s].z, g[s].w);
            *(uint2*)&xs[buf][row * 128 + ((off >> 1) ^ (row & 7)) * 8 + (off & 1) * 4] = u;
        }
    };
    // W staging: 3072 16B-slots (192 cols x 16 chunks), 48 DMA instrs (6/wave).
    // LDS linear; source pre-swizzled so LDS[col][ch] = W[col][ch ^ (col&7)].
    auto dma_w = [&](int sg, int buf) {
#pragma unroll
        for (int j = 0; j < 6; ++j) {
            const int slot0 = (wv * 6 + j) * 64;
            const int slot  = slot0 + lane;
            const int col   = slot >> 4, ch = slot & 15;
            dma16(Wtb + ((long)(sg * 192 + col)) * 128 + ((ch ^ (col & 7)) * 8),
                  &wsd[buf][slot0 * 8]);
        }
    };

    load_stage(0);
    dma_w(0, 0);
    write_stage(0);

    for (int sg = 0; sg < 8; ++sg) {
        __syncthreads();                      // drains DMA + x writes for sg
        if (sg + 1 < 8) {                     // prefetch next stage
            load_stage(sg + 1);
            dma_w(sg + 1, (sg + 1) & 1);
        }
        bf16x8 wf[3][4];
#pragma unroll
        for (int ntl = 0; ntl < 3; ++ntl)
#pragma unroll
            for (int kq = 0; kq < 4; ++kq) {
                const int col = colg * 48 + ntl * 16 + l15;
                wf[ntl][kq] = *(const bf16x8*)&wsd[sg & 1][col * 128
                                                           + (((kq * 4 + quad) ^ (col & 7))) * 8];
            }
#pragma unroll
        for (int mt = 0; mt < 2; ++mt)
#pragma unroll
            for (int kq = 0; kq < 4; ++kq) {
                const int row = rowg * 32 + mt * 16 + l15;
                bf16x8 a = *(const bf16x8*)&xs[sg & 1][row * 128
                                                       + ((kq * 4 + quad) ^ (row & 7)) * 8];
#pragma unroll
                for (int ntl = 0; ntl < 3; ++ntl)
                    acc[mt][ntl] = __builtin_amdgcn_mfma_f32_16x16x32_bf16(a, wf[ntl][kq], acc[mt][ntl], 0, 0, 0);
            }
        if (sg + 1 < 8) write_stage((sg + 1) & 1);  // other buffer; pre-barrier ok
    }
    // epilogue: C/D col=l15, row=quad*4+r
#pragma unroll
    for (int mt = 0; mt < 2; ++mt)
#pragma unroll
        for (int ntl = 0; ntl < 3; ++ntl) {
            const int c = colg * 48 + ntl * 16 + l15;
            const long tr0 = row0 + rowg * 32 + mt * 16 + quad * 4;
            if (c < 64) {
#pragma unroll
                for (int r = 0; r < 4; ++r)
                    qo[(tr0 + r) * HEAD + c] = f2bf(acc[mt][ntl][r] * S2LOG);
            } else if (c < 128) {
#pragma unroll
                for (int r = 0; r < 4; ++r)
                    ko[(tr0 + r) * HEAD + (c - 64)] = f2bf(acc[mt][ntl][r]);
            } else {
                const int b = (int)(tr0 >> 12), tloc = (int)(tr0 & 4095);
                uint2 pv;
                pv.x = pk_bf16(acc[mt][ntl][0], acc[mt][ntl][1]);
                pv.y = pk_bf16(acc[mt][ntl][2], acc[mt][ntl][3]);
                *(uint2*)&vt[((long)(b * HEAD + (c - 128))) * T_SEQ + tloc] = pv;
            }
        }
}

// ---------------- Kernel 2: flash attention, DMA-staged split-K -------------
// (round-2 known-good) 2176 blocks (544 segments x 4 batches), 256 threads.
// Block = one (segment, batch); 64-row q-tile, wave = 16-row strip. K+V chunk
// (16 KB) in shared LDS dbuf via global_load_lds, XOR-swizzled. <=4 chunks
// per segment. NO-MAX softmax: q pre-scaled to log2 units, p = exp2(s)
// directly (masked -> exp2(-30000) = 0). Partial = fp16 O/l + fp32 l.
__global__ __launch_bounds__(256, 3) void flash_seg(
    const unsigned short* __restrict__ qg,
    const unsigned short* __restrict__ kg,
    const unsigned short* __restrict__ vtg,
    __half* __restrict__ opart, float* __restrict__ ml)
{
    __shared__ __align__(16) unsigned short kv_s[2][8192]; // [buf][K 4096|V 4096]
    __shared__ __align__(16) unsigned short p_s[4][16 * 72];
    const int t0   = threadIdx.x;
    const int lane = t0 & 63;
    const int l15  = lane & 15, quad = lane >> 4;
    const int wv   = __builtin_amdgcn_readfirstlane(t0 >> 6);

    const int bid = (int)blockIdx.x;
    const int sid = (NSEG - 1) - (bid >> 2);   // heavy first
    const int b   = bid & 3;

    int kk = 0, pref = 0;
#pragma unroll
    for (int i = 0; i < 15; ++i) {
        const int cnt = 4 * (kk + 1);
        if (sid >= pref + cnt) { pref += cnt; ++kk; }
    }
    const int S   = kk + 1;
    const int rem = sid - pref;
    const int t   = kk * 4 + rem / S;
    const int si  = rem % S;
    const int r0  = t * 64;
    const int rw  = r0 + wv * 16;              // this wave's q-strip
    const int nck = t + 1;
    const int c0  = (si * nck) / S, c1 = ((si + 1) * nck) / S;
    const long bbase = (long)b * T_SEQ;
    const int gidx = b * NSEG + sid;

    bf16x8 qf[2];
#pragma unroll
    for (int h = 0; h < 2; ++h)
        qf[h] = *(const bf16x8*)&qg[(bbase + rw + l15) * HEAD + h * 32 + quad * 8];

    f32x4 o[4];
#pragma unroll
    for (int dt = 0; dt < 4; ++dt) o[dt] = (f32x4){0.f, 0.f, 0.f, 0.f};
    float lrun = 0.f;
    unsigned short* ps = p_s[wv];

    // DMA one K+V chunk: wave wv issues K jj={2wv,2wv+1}, V jj={2wv,2wv+1}.
    auto dma_chunk = [&](int key0, int buf) {
#pragma unroll
        for (int i = 0; i < 2; ++i) {
            const int jj  = wv * 2 + i;
            const int kl  = jj * 8 + (lane >> 3);
            const int dlg = (lane & 7) ^ ((lane >> 3) & 7);
            dma16(kg + (bbase + key0 + kl) * HEAD + dlg * 8,
                  &kv_s[buf][jj * 512]);
        }
#pragma unroll
        for (int i = 0; i < 2; ++i) {
            const int jj  = wv * 2 + i;
            const int dim = jj * 8 + (lane >> 3);
            const int klg = (lane & 7) ^ ((lane >> 3) & 7);
            dma16(vtg + ((long)(b * HEAD + dim)) * T_SEQ + key0 + klg * 8,
                  &kv_s[buf][4096 + jj * 512]);
        }
    };
    dma_chunk(c0 * 64, 0);

    for (int c = c0; c < c1; ++c) {
        const int key0 = c * 64;
        const int cur  = (c - c0) & 1;
        __syncthreads();                       // drain DMA(cur) + sync waves
        if (c + 1 < c1) dma_chunk((c + 1) * 64, cur ^ 1);

        // S^T = K Q^T : kf A-frags from swizzled LDS
        f32x4 st[4];
#pragma unroll
        for (int mt = 0; mt < 4; ++mt) {
            const int key_l = mt * 16 + l15;
            bf16x8 k0 = *(const bf16x8*)&kv_s[cur][key_l * 64 + ((quad    ) ^ (l15 & 7)) * 8];
            bf16x8 k1 = *(const bf16x8*)&kv_s[cur][key_l * 64 + ((quad + 4) ^ (l15 & 7)) * 8];
            f32x4 z = (f32x4){0.f, 0.f, 0.f, 0.f};
            z = __builtin_amdgcn_mfma_f32_16x16x32_bf16(k0, qf[0], z, 0, 0, 0);
            st[mt] = __builtin_amdgcn_mfma_f32_16x16x32_bf16(k1, qf[1], st[mt] = z, 0, 0, 0);
        }
        bf16x8 vf[4][2];
#pragma unroll
        for (int dt = 0; dt < 4; ++dt) {
            const int dim = dt * 16 + l15;
            vf[dt][0] = *(const bf16x8*)&kv_s[cur][4096 + dim * 64 + ((quad    ) ^ (l15 & 7)) * 8];
            vf[dt][1] = *(const bf16x8*)&kv_s[cur][4096 + dim * 64 + ((quad + 4) ^ (l15 & 7)) * 8];
        }
        if (key0 + 63 > rw) {                  // causal mask (diagonal chunk)
            const int row = rw + l15;
#pragma unroll
            for (int mt = 0; mt < 4; ++mt)
#pragma unroll
                for (int r = 0; r < 4; ++r) {
                    const int key = key0 + mt * 16 + quad * 4 + r;
                    st[mt][r] = (key <= row) ? st[mt][r] : -30000.f;
                }
        }
        // no-max softmax: p = exp2(s) directly, stats lane-local (lane = q-row)
        float psum = 0.f;
#pragma unroll
        for (int mt = 0; mt < 4; ++mt) {
            float e0 = exp2f(st[mt][0]), e1 = exp2f(st[mt][1]);
            float e2 = exp2f(st[mt][2]), e3 = exp2f(st[mt][3]);
            psum += (e0 + e1) + (e2 + e3);
            *(unsigned int*)&ps[l15 * 72 + mt * 16 + quad * 4]     = pk_bf16(e0, e1);
            *(unsigned int*)&ps[l15 * 72 + mt * 16 + quad * 4 + 2] = pk_bf16(e2, e3);
        }
        psum += __shfl_xor(psum, 16);
        psum += __shfl_xor(psum, 32);
        lrun += psum;
        __builtin_amdgcn_wave_barrier();
        bf16x8 pf[2];
#pragma unroll
        for (int g = 0; g < 2; ++g)
            pf[g] = *(const bf16x8*)&ps[l15 * 72 + g * 32 + quad * 8];
        __builtin_amdgcn_wave_barrier();
#pragma unroll
        for (int dt = 0; dt < 4; ++dt) {
            o[dt] = __builtin_amdgcn_mfma_f32_16x16x32_bf16(vf[dt][0], pf[0], o[dt], 0, 0, 0);
            o[dt] = __builtin_amdgcn_mfma_f32_16x16x32_bf16(vf[dt][1], pf[1], o[dt], 0, 0, 0);
        }
    }

    // partial write: opart[gidx][row 64][dim 64] = O/l (fp16); l per q-row.
    // inv is lane-local per q-row; guard fully-masked strips (l == 0).
    const float inv = (lrun > 0.f) ? 1.f / lrun : 0.f;
    __half* op = opart + (long)gidx * 4096;
#pragma unroll
    for (int dt = 0; dt < 4; ++dt) {
        __half2 h0 = __floats2half2_rn(o[dt][0] * inv, o[dt][1] * inv);
        __half2 h1 = __floats2half2_rn(o[dt][2] * inv, o[dt][3] * inv);
        uint2 u; __builtin_memcpy(&u.x, &h0, 4); __builtin_memcpy(&u.y, &h1, 4);
        *(uint2*)&op[(wv * 16 + l15) * HEAD + dt * 16 + quad * 4] = u;
    }
    if (quad == 0)
        ml[(long)gidx * 64 + wv * 16 + l15] = lrun;
}

// ---------------- Kernel 3: merge split-K partials (l-weighted average) -----
// 512 blocks: (b, tile, row-half). 2 blocks/CU, 8 floats/thread.
__global__ __launch_bounds__(256) void merge_seg(
    const __half* __restrict__ opart, const float* __restrict__ ml,
    float* __restrict__ out)
{
    const int bid = blockIdx.x;
    const int half = bid & 1, t = (bid >> 1) & 63, b = bid >> 7;
    const int kk = t >> 2, S = kk + 1;
    const int base_sid = 2 * kk * (kk + 1) + (t & 3) * S;
    const int tid = threadIdx.x;
    const int row = half * 32 + (tid >> 3), col0 = (tid & 7) * 8;

    float acc[8];
#pragma unroll
    for (int j = 0; j < 8; ++j) acc[j] = 0.f;
    float L = 0.f;
    for (int si = 0; si < S; ++si) {
        const long g = (long)(b * NSEG + base_sid + si);
        const float l = ml[g * 64 + row];
        L += l;
        const __half* op = opart + g * 4096 + row * 64 + col0;
        uint4 u = *(const uint4*)op;
        __half2 h01, h23, h45, h67;
        __builtin_memcpy(&h01, &u.x, 4); __builtin_memcpy(&h23, &u.y, 4);
        __builtin_memcpy(&h45, &u.z, 4); __builtin_memcpy(&h67, &u.w, 4);
        float2 f01 = __half22float2(h01), f23 = __half22float2(h23);
        float2 f45 = __half22float2(h45), f67 = __half22float2(h67);
        acc[0] += l * f01.x; acc[1] += l * f01.y;
        acc[2] += l * f23.x; acc[3] += l * f23.y;
        acc[4] += l * f45.x; acc[5] += l * f45.y;
        acc[6] += l * f67.x; acc[7] += l * f67.y;
    }
    const float inv = 1.f / L;     // L > 0: every q-row sees its diagonal key
    float* dst = out + ((long)(b * T_SEQ + t * 64 + row)) * HEAD + col0;
#pragma unroll
    for (int h = 0; h < 2; ++h) {
        float4 ov = {acc[h * 4] * inv, acc[h * 4 + 1] * inv,
                     acc[h * 4 + 2] * inv, acc[h * 4 + 3] * inv};
        *(float4*)(dst + h * 4) = ov;
    }
}

extern "C" void kernel_launch(void* const* d_in, const int* in_sizes, int n_in,
                              void* d_out, int out_size, void* d_ws, size_t ws_size,
                              hipStream_t stream) {
    const float* x  = (const float*)d_in[0];
    const float* Wq = (const float*)d_in[1];
    const float* bq = (const float*)d_in[2];
    const float* Wk = (const float*)d_in[3];
    const float* bk = (const float*)d_in[4];
    const float* Wv = (const float*)d_in[5];
    const float* bv = (const float*)d_in[6];
    float* outp = (float*)d_out;

    char* wsb = (char*)d_ws;
    unsigned short* wtb = (unsigned short*)(wsb);                  // 384 KB
    unsigned short* qw  = (unsigned short*)(wsb + 393216);         // 2 MB
    unsigned short* kw  = (unsigned short*)(wsb + 2490368);        // 2 MB
    unsigned short* vtw = (unsigned short*)(wsb + 4587520);        // 2 MB
    __half* opart       = (__half*)(wsb + 6684672);                // 17.8 MB
    float*  mlp         = (float*)(wsb + 24510464);                // 0.6 MB

    prep_w<<<dim3(48), dim3(256), 0, stream>>>(Wq, Wk, Wv, wtb);
    qkv_mfma<<<dim3(256), dim3(512), 0, stream>>>(
        x, wtb, bq, bk, bv, qw, kw, vtw);
    flash_seg<<<dim3(NSEG * NBATCH), dim3(256), 0, stream>>>(qw, kw, vtw, opart, mlp);
    merge_seg<<<dim3(512), dim3(256), 0, stream>>>(opart, mlp, outp);
}